// Round 5
// baseline (1460.585 us; speedup 1.0000x reference)
//
#include <hip/hip_runtime.h>

#define NN 100000
#define EE 1600000
#define GG 256
#define EPS 1e-5f
#define KB2 ((NN + 511) >> 9)        // 196 buckets of 512 dsts
#define EPB 4096                     // edges per block (bcnt/passA)
#define EBLK ((EE + EPB - 1) / EPB)  // 391
#define NB256 ((NN + 255) / 256)     // 391
#define DPB 64                       // dsts per block in k_layer3
#define LBLK ((NN + DPB - 1) / DPB)  // 1563
#define SRCMASK 0xFFFFF              // src fits in 17 bits; 20-bit field

// ---------- stage 1: per-bucket edge counts ----------
__global__ void k_bcnt(const int* __restrict__ ei, int* __restrict__ bcnt) {
  __shared__ int cnt[KB2];
  int t = threadIdx.x;
  for (int i = t; i < KB2; i += 256) cnt[i] = 0;
  __syncthreads();
  int e0 = blockIdx.x * EPB;
#pragma unroll
  for (int j = 0; j < 16; ++j) {
    int e = e0 + j * 256 + t;
    if (e < EE) atomicAdd(&cnt[ei[EE + e] >> 9], 1);
  }
  __syncthreads();
  for (int i = t; i < KB2; i += 256)
    if (cnt[i] > 0) atomicAdd(&bcnt[i], cnt[i]);
}

// ---------- stage 2: scan bucket counts -> bucket bases ----------
__global__ void k_bscan(const int* __restrict__ bcnt, int* __restrict__ bbase,
                        int* __restrict__ bfill, int* __restrict__ row) {
  __shared__ int s[256];
  int t = threadIdx.x;
  int v = (t < KB2) ? bcnt[t] : 0;
  s[t] = v;
  __syncthreads();
  for (int off = 1; off < 256; off <<= 1) {
    int add = (t >= off) ? s[t - off] : 0;
    __syncthreads();
    s[t] += add;
    __syncthreads();
  }
  if (t < KB2) {
    int e = s[t] - v;
    bbase[t] = e;
    bfill[t] = e;
  }
  if (t == 0) {
    bbase[KB2] = EE;
    row[NN] = EE;
  }
}

// ---------- stage 3: bucketed dump of (src,dst) pairs ----------
__global__ void k_passA(const int* __restrict__ ei, int* __restrict__ bfill,
                        int2* __restrict__ tmp) {
  __shared__ int cnt[KB2], cur[KB2], base[KB2];
  int t = threadIdx.x;
  for (int b = t; b < KB2; b += 256) { cnt[b] = 0; cur[b] = 0; }
  __syncthreads();
  int e0 = blockIdx.x * EPB;
  int myb[16];
#pragma unroll
  for (int j = 0; j < 16; ++j) {
    int e = e0 + j * 256 + t;
    int bb = -1;
    if (e < EE) bb = ei[EE + e] >> 9;
    myb[j] = bb;
    if (bb >= 0) atomicAdd(&cnt[bb], 1);
  }
  __syncthreads();
  for (int b = t; b < KB2; b += 256)
    if (cnt[b] > 0) base[b] = atomicAdd(&bfill[b], cnt[b]);
  __syncthreads();
#pragma unroll
  for (int j = 0; j < 16; ++j) {
    int e = e0 + j * 256 + t;
    int bb = myb[j];
    if (bb >= 0) {
      int slot = base[bb] + atomicAdd(&cur[bb], 1);
      tmp[slot] = make_int2(ei[e], ei[EE + e]);
    }
  }
}

// ---------- stage 4: per-bucket hist+scan+scatter; emits row, dinv, xd, packed csr ----------
__global__ void k_bucket(const int2* __restrict__ tmp, const int* __restrict__ bbase,
                         const float* __restrict__ x, int* __restrict__ csr,
                         int* __restrict__ row, float* __restrict__ dinv,
                         float4* __restrict__ xd) {
  __shared__ int cnt[512], s[512], fillp[512];
  int b = blockIdx.x, t = threadIdx.x;
  int nb = b << 9;
  int e0 = bbase[b], e1 = bbase[b + 1];
  cnt[t] = 0;
  cnt[t + 256] = 0;
  __syncthreads();
  for (int e = e0 + t; e < e1; e += 256) atomicAdd(&cnt[tmp[e].y & 511], 1);
  __syncthreads();
  s[t] = cnt[t];
  s[t + 256] = cnt[t + 256];
  __syncthreads();
  for (int off = 1; off < 512; off <<= 1) {
    int i1 = t + 256;
    int v0 = (t >= off) ? s[t - off] : 0;
    int v1 = (i1 >= off) ? s[i1 - off] : 0;
    __syncthreads();
    s[t] += v0;
    s[i1] += v1;
    __syncthreads();
  }
#pragma unroll
  for (int k = 0; k < 2; ++k) {
    int i = t + k * 256;
    int excl = s[i] - cnt[i];
    fillp[i] = excl;
    int dst = nb + i;
    if (dst < NN) {
      row[dst] = e0 + excl;
      float d = rsqrtf((float)cnt[i] + 1.0f);
      dinv[dst] = d;
      xd[dst] = make_float4(x[dst * 3] * d, x[dst * 3 + 1] * d, x[dst * 3 + 2] * d, 0.f);
    }
  }
  __syncthreads();
  for (int e = e0 + t; e < e1; e += 256) {
    int2 ed = tmp[e];
    int dl = ed.y & 511;
    int slot = atomicAdd(&fillp[dl], 1);
    csr[e0 + slot] = ed.x | ((dl & 255) << 20);  // pack src | (dst&255)<<20
  }
}

// ---------- layer 0: edge-parallel 3-ch aggregate + fused 3->64 matmul+BN+ReLU ----------
__global__ void k_agg3f(const float4* __restrict__ xd, const int* __restrict__ row,
                        const int* __restrict__ csr, const float* __restrict__ dinv,
                        const float* __restrict__ W, const float* __restrict__ b,
                        const float* __restrict__ gam, const float* __restrict__ bet,
                        const float* __restrict__ rm, const float* __restrict__ rv,
                        float4* __restrict__ outb) {
  __shared__ float acc[256 * 5];  // stride 5: spreads ds_add across all banks
  int t = threadIdx.x;
  int base = blockIdx.x << 8;
  int nval = min(256, NN - base);
  if (t < nval) {
    float4 v = xd[base + t];  // self term (pre-scaled by dinv)
    float* a = &acc[t * 5];
    a[0] = v.x; a[1] = v.y; a[2] = v.z;
  }
  int e0 = row[base];
  int e1 = row[base + nval];
  __syncthreads();
  for (int eb = e0; eb < e1; eb += 1024) {
#pragma unroll
    for (int u = 0; u < 4; ++u) {
      int e = eb + u * 256 + t;
      if (e < e1) {
        int v = csr[e];
        int src = v & SRCMASK;
        int dl = v >> 20;  // dst&255 == dst_local (256-aligned blocks)
        float4 xv = xd[src];
        float* a = &acc[dl * 5];
        unsafeAtomicAdd(a + 0, xv.x);
        unsafeAtomicAdd(a + 1, xv.y);
        unsafeAtomicAdd(a + 2, xv.z);  // w component is always 0: skip
      }
    }
  }
  __syncthreads();
  int sub = t & 15, grp = t >> 4;
  const float4* W4 = (const float4*)W;
  float4 bb = ((const float4*)b)[sub];
  float4 g4 = ((const float4*)gam)[sub];
  float4 be4 = ((const float4*)bet)[sub];
  float4 rm4 = ((const float4*)rm)[sub];
  float4 rv4 = ((const float4*)rv)[sub];
  float scx = g4.x * rsqrtf(rv4.x + EPS), shx = be4.x - rm4.x * scx;
  float scy = g4.y * rsqrtf(rv4.y + EPS), shy = be4.y - rm4.y * scy;
  float scz = g4.z * rsqrtf(rv4.z + EPS), shz = be4.z - rm4.z * scz;
  float scw = g4.w * rsqrtf(rv4.w + EPS), shw = be4.w - rm4.w * scw;
  float4 w0 = W4[0 * 16 + sub], w1 = W4[1 * 16 + sub], w2 = W4[2 * 16 + sub];
#pragma unroll
  for (int p = 0; p < 16; ++p) {
    int l = p * 16 + grp;
    if (l >= nval) continue;
    int dst = base + l;
    float a0 = acc[l * 5], a1 = acc[l * 5 + 1], a2 = acc[l * 5 + 2];
    float d = dinv[dst];
    float4 o;
    o.x = fmaf(a0, w0.x, fmaf(a1, w1.x, a2 * w2.x));
    o.y = fmaf(a0, w0.y, fmaf(a1, w1.y, a2 * w2.y));
    o.z = fmaf(a0, w0.z, fmaf(a1, w1.z, a2 * w2.z));
    o.w = fmaf(a0, w0.w, fmaf(a1, w1.w, a2 * w2.w));
    o.x = fmaxf(fmaf(fmaf(o.x, d, bb.x), scx, shx), 0.f) * d;  // BN+ReLU, pre-scale next
    o.y = fmaxf(fmaf(fmaf(o.y, d, bb.y), scy, shy), 0.f) * d;
    o.z = fmaxf(fmaf(fmaf(o.z, d, bb.z), scz, shz), 0.f) * d;
    o.w = fmaxf(fmaf(fmaf(o.w, d, bb.w), scw, shw), 0.f) * d;
    outb[(size_t)dst * 16 + sub] = o;
  }
}

// ---------- layers 1/2: edge-parallel gather + LDS accumulate + fused matmul+BN+ReLU ----------
template <bool SCALE_OUT>
__global__ void k_layer3(const float4* __restrict__ xs, const int* __restrict__ row,
                         const int* __restrict__ csr, const float* __restrict__ dinv,
                         const float* __restrict__ W, const float* __restrict__ b,
                         const float* __restrict__ gam, const float* __restrict__ bet,
                         const float* __restrict__ rm, const float* __restrict__ rv,
                         float4* __restrict__ outb) {
  __shared__ __align__(16) float acc[DPB * 68];  // stride 68: b128-able, conflict-spread
  int t = threadIdx.x;
  int base = blockIdx.x * DPB;
  int nval = min(DPB, NN - base);
  int sub = t & 15, grp = t >> 4;
#pragma unroll
  for (int p = 0; p < 4; ++p) {
    int l = p * 16 + grp;
    if (l < nval) ((float4*)(acc + l * 68))[sub] = xs[(size_t)(base + l) * 16 + sub];
  }
  int e0 = row[base];
  int e1 = row[base + nval];
  __syncthreads();
  int base8 = base & 255;
  // group g handles edges e0+g, e0+g+16, ... ; 8 gathers in flight per group
  for (int eb = e0; eb < e1; eb += 128) {
#pragma unroll
    for (int u = 0; u < 8; ++u) {
      int e = eb + u * 16 + grp;
      if (e < e1) {
        int v = csr[e];
        int src = v & SRCMASK;
        int dl = (v >> 20) - base8;
        float4 xv = xs[(size_t)src * 16 + sub];
        float* a = acc + dl * 68 + sub * 4;
        unsafeAtomicAdd(a + 0, xv.x);
        unsafeAtomicAdd(a + 1, xv.y);
        unsafeAtomicAdd(a + 2, xv.z);
        unsafeAtomicAdd(a + 3, xv.w);
      }
    }
  }
  __syncthreads();
  const float4* W4 = (const float4*)W;
  float4 bb = ((const float4*)b)[sub];
  float4 g4 = ((const float4*)gam)[sub];
  float4 be4 = ((const float4*)bet)[sub];
  float4 rm4 = ((const float4*)rm)[sub];
  float4 rv4 = ((const float4*)rv)[sub];
  float scx = g4.x * rsqrtf(rv4.x + EPS), shx = be4.x - rm4.x * scx;
  float scy = g4.y * rsqrtf(rv4.y + EPS), shy = be4.y - rm4.y * scy;
  float scz = g4.z * rsqrtf(rv4.z + EPS), shz = be4.z - rm4.z * scz;
  float scw = g4.w * rsqrtf(rv4.w + EPS), shw = be4.w - rm4.w * scw;
#pragma unroll
  for (int p = 0; p < 4; ++p) {
    int l = p * 16 + grp;
    if (l >= nval) continue;
    const float4* arow = (const float4*)(acc + l * 68);
    float4 s4 = make_float4(0.f, 0.f, 0.f, 0.f);
#pragma unroll
    for (int k4 = 0; k4 < 16; ++k4) {
      float4 av = arow[k4];
      float4 wv0 = W4[(4 * k4 + 0) * 16 + sub];
      float4 wv1 = W4[(4 * k4 + 1) * 16 + sub];
      float4 wv2 = W4[(4 * k4 + 2) * 16 + sub];
      float4 wv3 = W4[(4 * k4 + 3) * 16 + sub];
      s4.x = fmaf(av.x, wv0.x, s4.x); s4.y = fmaf(av.x, wv0.y, s4.y);
      s4.z = fmaf(av.x, wv0.z, s4.z); s4.w = fmaf(av.x, wv0.w, s4.w);
      s4.x = fmaf(av.y, wv1.x, s4.x); s4.y = fmaf(av.y, wv1.y, s4.y);
      s4.z = fmaf(av.y, wv1.z, s4.z); s4.w = fmaf(av.y, wv1.w, s4.w);
      s4.x = fmaf(av.z, wv2.x, s4.x); s4.y = fmaf(av.z, wv2.y, s4.y);
      s4.z = fmaf(av.z, wv2.z, s4.z); s4.w = fmaf(av.z, wv2.w, s4.w);
      s4.x = fmaf(av.w, wv3.x, s4.x); s4.y = fmaf(av.w, wv3.y, s4.y);
      s4.z = fmaf(av.w, wv3.z, s4.z); s4.w = fmaf(av.w, wv3.w, s4.w);
    }
    float d = dinv[base + l];
    float4 o;
    o.x = fmaxf(fmaf(fmaf(s4.x, d, bb.x), scx, shx), 0.f);
    o.y = fmaxf(fmaf(fmaf(s4.y, d, bb.y), scy, shy), 0.f);
    o.z = fmaxf(fmaf(fmaf(s4.z, d, bb.z), scz, shz), 0.f);
    o.w = fmaxf(fmaf(fmaf(s4.w, d, bb.w), scw, shw), 0.f);
    if (SCALE_OUT) { o.x *= d; o.y *= d; o.z *= d; o.w *= d; }
    outb[(size_t)(base + l) * 16 + sub] = o;
  }
}

// ---------- fused pooling + MLP: one block per graph, no atomics ----------
__device__ __forceinline__ int lower_bound(const int* __restrict__ b, int target) {
  int lo = 0, hi = NN;
  while (lo < hi) {
    int m = (lo + hi) >> 1;
    if (b[m] < target) lo = m + 1; else hi = m;
  }
  return lo;
}

__global__ void k_poolmlp(const float* __restrict__ feat, const int* __restrict__ bidx,
                          const float* __restrict__ mW1, const float* __restrict__ mb1,
                          const float* __restrict__ mW2, const float* __restrict__ mb2,
                          const float* __restrict__ mW3, const float* __restrict__ mb3,
                          float* __restrict__ out) {
  __shared__ float ssum[4][64], smax[4][64], xg[128], h1[32], h2[16];
  int g = blockIdx.x, t = threadIdx.x;  // 256 threads
  int c = t & 63, q = t >> 6;
  int lo = lower_bound(bidx, g);
  int hi = lower_bound(bidx, g + 1);
  float s = 0.f, m = 0.f;  // feat >= 0 post-ReLU; empty graph -> 0 matches reference
  for (int i = lo + q; i < hi; i += 4) {
    float v = feat[(size_t)i * 64 + c];
    s += v;
    m = fmaxf(m, v);
  }
  ssum[q][c] = s;
  smax[q][c] = m;
  __syncthreads();
  if (q == 0) {
    float cs = ssum[0][c] + ssum[1][c] + ssum[2][c] + ssum[3][c];
    float cm = fmaxf(fmaxf(smax[0][c], smax[1][c]), fmaxf(smax[2][c], smax[3][c]));
    float cnt = fmaxf((float)(hi - lo), 1.0f);
    xg[c] = cs / cnt;
    xg[64 + c] = cm;
  }
  __syncthreads();
  if (t < 32) {
    float a = mb1[t];
    for (int k = 0; k < 128; ++k) a = fmaf(xg[k], mW1[k * 32 + t], a);
    h1[t] = fmaxf(a, 0.f);
  }
  __syncthreads();
  if (t < 16) {
    float a = mb2[t];
    for (int k = 0; k < 32; ++k) a = fmaf(h1[k], mW2[k * 16 + t], a);
    h2[t] = fmaxf(a, 0.f);
  }
  __syncthreads();
  if (t == 0) {
    float a = mb3[0];
    for (int k = 0; k < 16; ++k) a = fmaf(h2[k], mW3[k], a);
    out[g] = a;
  }
}

extern "C" void kernel_launch(void* const* d_in, const int* in_sizes, int n_in,
                              void* d_out, int out_size, void* d_ws, size_t ws_size,
                              hipStream_t stream) {
  const float* x = (const float*)d_in[0];
  const int* ei = (const int*)d_in[1];
  const int* bidx = (const int*)d_in[2];
  const float *W[3], *b[3], *gam[3], *bet[3], *rm[3], *rv[3];
  for (int l = 0; l < 3; ++l) {
    W[l] = (const float*)d_in[3 + 6 * l];
    b[l] = (const float*)d_in[4 + 6 * l];
    gam[l] = (const float*)d_in[5 + 6 * l];
    bet[l] = (const float*)d_in[6 + 6 * l];
    rm[l] = (const float*)d_in[7 + 6 * l];
    rv[l] = (const float*)d_in[8 + 6 * l];
  }
  const float* mW1 = (const float*)d_in[21];
  const float* mb1 = (const float*)d_in[22];
  const float* mW2 = (const float*)d_in[23];
  const float* mb2 = (const float*)d_in[24];
  const float* mW3 = (const float*)d_in[25];
  const float* mb3 = (const float*)d_in[26];
  float* out = (float*)d_out;

  char* ws = (char*)d_ws;
  size_t off = 0;
  auto alloc = [&](size_t bytes) {
    void* p = ws + off;
    off = (off + bytes + 1023) & ~(size_t)1023;
    return p;
  };
  float* dinv = (float*)alloc(NN * 4);
  int* row = (int*)alloc((NN + 1) * 4);
  int* csr = (int*)alloc((size_t)EE * 4);
  int* bcnt = (int*)alloc(256 * 4);
  int* bbase = (int*)alloc(256 * 4);
  int* bfill = (int*)alloc(256 * 4);
  float4* xd = (float4*)alloc((size_t)NN * 16);
  float* bufA = (float*)alloc((size_t)NN * 64 * 4);
  float* bufB = (float*)alloc((size_t)NN * 64 * 4);
  int2* tmp = (int2*)bufA;  // alias: tmp consumed by k_bucket before bufA is written

  hipMemsetAsync(bcnt, 0, 256 * 4, stream);

  // graph structure: bucket count -> scan -> bucketed dump -> per-bucket build
  k_bcnt<<<EBLK, 256, 0, stream>>>(ei, bcnt);
  k_bscan<<<1, 256, 0, stream>>>(bcnt, bbase, bfill, row);
  k_passA<<<EBLK, 256, 0, stream>>>(ei, bfill, tmp);
  k_bucket<<<KB2, 256, 0, stream>>>(tmp, bbase, x, csr, row, dinv, xd);

  // layer 0: edge-parallel 3-ch aggregate + fused matmul+BN+ReLU (pre-scaled out)
  k_agg3f<<<NB256, 256, 0, stream>>>(xd, row, csr, dinv, W[0], b[0], gam[0], bet[0],
                                     rm[0], rv[0], (float4*)bufA);
  // layer 1: edge-parallel fused layer, output pre-scaled for layer-2 gather
  k_layer3<true><<<LBLK, 256, 0, stream>>>((const float4*)bufA, row, csr, dinv, W[1], b[1],
                                           gam[1], bet[1], rm[1], rv[1], (float4*)bufB);
  // layer 2: fused, unscaled output (final features)
  k_layer3<false><<<LBLK, 256, 0, stream>>>((const float4*)bufB, row, csr, dinv, W[2], b[2],
                                            gam[2], bet[2], rm[2], rv[2], (float4*)bufA);
  // pooling (segmented, batch_idx sorted, no atomics) + graph MLP
  k_poolmlp<<<GG, 256, 0, stream>>>(bufA, bidx, mW1, mb1, mW2, mb2, mW3, mb3, out);
}

// Round 6
// 420.321 us; speedup vs baseline: 3.4749x; 3.4749x over previous
//
#include <hip/hip_runtime.h>

#define NN 100000
#define EE 1600000
#define GG 256
#define EPS 1e-5f
#define KB2 ((NN + 511) >> 9)        // 196 buckets of 512 dsts
#define EPB 4096                     // edges per block (bcnt/passA)
#define EBLK ((EE + EPB - 1) / EPB)  // 391
#define NB256 ((NN + 255) / 256)     // 391

// ---------- stage 1: per-bucket edge counts ----------
__global__ void k_bcnt(const int* __restrict__ ei, int* __restrict__ bcnt) {
  __shared__ int cnt[KB2];
  int t = threadIdx.x;
  for (int i = t; i < KB2; i += 256) cnt[i] = 0;
  __syncthreads();
  int e0 = blockIdx.x * EPB;
#pragma unroll
  for (int j = 0; j < 16; ++j) {
    int e = e0 + j * 256 + t;
    if (e < EE) atomicAdd(&cnt[ei[EE + e] >> 9], 1);
  }
  __syncthreads();
  for (int i = t; i < KB2; i += 256)
    if (cnt[i] > 0) atomicAdd(&bcnt[i], cnt[i]);
}

// ---------- stage 2: scan bucket counts -> bucket bases ----------
__global__ void k_bscan(const int* __restrict__ bcnt, int* __restrict__ bbase,
                        int* __restrict__ bfill, int* __restrict__ row) {
  __shared__ int s[256];
  int t = threadIdx.x;
  int v = (t < KB2) ? bcnt[t] : 0;
  s[t] = v;
  __syncthreads();
  for (int off = 1; off < 256; off <<= 1) {
    int add = (t >= off) ? s[t - off] : 0;
    __syncthreads();
    s[t] += add;
    __syncthreads();
  }
  if (t < KB2) {
    int e = s[t] - v;
    bbase[t] = e;
    bfill[t] = e;
  }
  if (t == 0) {
    bbase[KB2] = EE;
    row[NN] = EE;
  }
}

// ---------- stage 3: bucketed dump of (src,dst) pairs ----------
__global__ void k_passA(const int* __restrict__ ei, int* __restrict__ bfill,
                        int2* __restrict__ tmp) {
  __shared__ int cnt[KB2], cur[KB2], base[KB2];
  int t = threadIdx.x;
  for (int b = t; b < KB2; b += 256) { cnt[b] = 0; cur[b] = 0; }
  __syncthreads();
  int e0 = blockIdx.x * EPB;
  int myb[16];
#pragma unroll
  for (int j = 0; j < 16; ++j) {
    int e = e0 + j * 256 + t;
    int bb = -1;
    if (e < EE) bb = ei[EE + e] >> 9;
    myb[j] = bb;
    if (bb >= 0) atomicAdd(&cnt[bb], 1);
  }
  __syncthreads();
  for (int b = t; b < KB2; b += 256)
    if (cnt[b] > 0) base[b] = atomicAdd(&bfill[b], cnt[b]);
  __syncthreads();
#pragma unroll
  for (int j = 0; j < 16; ++j) {
    int e = e0 + j * 256 + t;
    int bb = myb[j];
    if (bb >= 0) {
      int slot = base[bb] + atomicAdd(&cur[bb], 1);
      tmp[slot] = make_int2(ei[e], ei[EE + e]);
    }
  }
}

// ---------- stage 4: per-bucket hist+scan+scatter; emits row, dinv, xd, csr ----------
__global__ void k_bucket(const int2* __restrict__ tmp, const int* __restrict__ bbase,
                         const float* __restrict__ x, int* __restrict__ csr,
                         int* __restrict__ row, float* __restrict__ dinv,
                         float4* __restrict__ xd) {
  __shared__ int cnt[512], s[512], fillp[512];
  int b = blockIdx.x, t = threadIdx.x;
  int nb = b << 9;
  int e0 = bbase[b], e1 = bbase[b + 1];
  cnt[t] = 0;
  cnt[t + 256] = 0;
  __syncthreads();
  for (int e = e0 + t; e < e1; e += 256) atomicAdd(&cnt[tmp[e].y & 511], 1);
  __syncthreads();
  s[t] = cnt[t];
  s[t + 256] = cnt[t + 256];
  __syncthreads();
  for (int off = 1; off < 512; off <<= 1) {
    int i1 = t + 256;
    int v0 = (t >= off) ? s[t - off] : 0;
    int v1 = (i1 >= off) ? s[i1 - off] : 0;
    __syncthreads();
    s[t] += v0;
    s[i1] += v1;
    __syncthreads();
  }
#pragma unroll
  for (int k = 0; k < 2; ++k) {
    int i = t + k * 256;
    int excl = s[i] - cnt[i];
    fillp[i] = excl;
    int dst = nb + i;
    if (dst < NN) {
      row[dst] = e0 + excl;
      float d = rsqrtf((float)cnt[i] + 1.0f);
      dinv[dst] = d;
      xd[dst] = make_float4(x[dst * 3] * d, x[dst * 3 + 1] * d, x[dst * 3 + 2] * d, 0.f);
    }
  }
  __syncthreads();
  for (int e = e0 + t; e < e1; e += 256) {
    int2 ed = tmp[e];
    int slot = atomicAdd(&fillp[ed.y & 511], 1);
    csr[e0 + slot] = ed.x;  // plain src index
  }
}

// ---------- layer 0: node-parallel 3-ch aggregate ----------
__global__ void k_agg3(const float4* __restrict__ xd, const int* __restrict__ row,
                       const int* __restrict__ csr, const float* __restrict__ dinv,
                       float4* __restrict__ xt) {
  int n = blockIdx.x * 256 + threadIdx.x;
  if (n >= NN) return;
  int s0 = row[n], s1 = row[n + 1];
  float4 a = xd[n];
  float ax = a.x, ay = a.y, az = a.z;
  int i = s0;
  for (; i + 8 <= s1; i += 8) {
    int idx[8];
#pragma unroll
    for (int j = 0; j < 8; ++j) idx[j] = csr[i + j];
    float4 v[8];
#pragma unroll
    for (int j = 0; j < 8; ++j) v[j] = xd[idx[j]];
#pragma unroll
    for (int j = 0; j < 8; ++j) { ax += v[j].x; ay += v[j].y; az += v[j].z; }
  }
  for (; i < s1; ++i) {
    float4 v = xd[csr[i]];
    ax += v.x; ay += v.y; az += v.z;
  }
  float d = dinv[n];
  xt[n] = make_float4(ax * d, ay * d, az * d, 0.f);
}

// bufA[n,c] = relu(BN(xt[n,:3] @ W0[:,c] + b[c])) * dinv[n]   (pre-scaled for next gather)
__global__ void k_mm3bn(const float4* __restrict__ xt, const float* __restrict__ W,
                        const float* __restrict__ b, const float* __restrict__ gam,
                        const float* __restrict__ bet, const float* __restrict__ rm,
                        const float* __restrict__ rv, const float* __restrict__ dinv,
                        float* __restrict__ out) {
  int t = blockIdx.x * 256 + threadIdx.x;
  int n = t >> 6, c = t & 63;
  if (n >= NN) return;
  float4 xv = xt[n];
  float acc = b[c];
  acc = fmaf(xv.x, W[c], acc);
  acc = fmaf(xv.y, W[64 + c], acc);
  acc = fmaf(xv.z, W[128 + c], acc);
  float sc = gam[c] * rsqrtf(rv[c] + EPS);
  float sh = bet[c] - rm[c] * sc;
  out[(size_t)n * 64 + c] = fmaxf(fmaf(acc, sc, sh), 0.f) * dinv[n];
}

// ---------- fused layer: gather(xs) -> *dinv -> @W + b -> BN -> ReLU [-> *dinv] ----------
// R4-proven: 16 threads/node, float4/lane, register accumulation, LDS exchange for matmul.
template <bool SCALE_OUT>
__global__ void k_layer2(const float4* __restrict__ xs, const int* __restrict__ row,
                         const int* __restrict__ csr, const float* __restrict__ dinv,
                         const float* __restrict__ W, const float* __restrict__ b,
                         const float* __restrict__ gam, const float* __restrict__ bet,
                         const float* __restrict__ rm, const float* __restrict__ rv,
                         float4* __restrict__ out) {
  __shared__ float sh[16][68];
  int t = blockIdx.x * 256 + threadIdx.x;
  int n = t >> 4, sub = t & 15;
  int local = threadIdx.x >> 4;
  if (n >= NN) return;  // N = 16*6250 exactly: no partial blocks, barrier-safe
  int s0 = row[n], s1 = row[n + 1];
  float4 a = xs[(size_t)n * 16 + sub];
  int i = s0;
  for (; i + 8 <= s1; i += 8) {
    int idx[8];
#pragma unroll
    for (int j = 0; j < 8; ++j) idx[j] = csr[i + j];
    float4 v[8];
#pragma unroll
    for (int j = 0; j < 8; ++j) v[j] = xs[(size_t)idx[j] * 16 + sub];
#pragma unroll
    for (int j = 0; j < 8; ++j) {
      a.x += v[j].x; a.y += v[j].y; a.z += v[j].z; a.w += v[j].w;
    }
  }
  for (; i < s1; ++i) {
    float4 v = xs[(size_t)csr[i] * 16 + sub];
    a.x += v.x; a.y += v.y; a.z += v.z; a.w += v.w;
  }
  float d = dinv[n];
  sh[local][sub * 4 + 0] = a.x * d;
  sh[local][sub * 4 + 1] = a.y * d;
  sh[local][sub * 4 + 2] = a.z * d;
  sh[local][sub * 4 + 3] = a.w * d;
  __syncthreads();
  const float4* W4 = (const float4*)W;
  float4 acc = ((const float4*)b)[sub];
#pragma unroll 8
  for (int k = 0; k < 64; ++k) {
    float xv = sh[local][k];
    float4 w = W4[k * 16 + sub];
    acc.x = fmaf(xv, w.x, acc.x);
    acc.y = fmaf(xv, w.y, acc.y);
    acc.z = fmaf(xv, w.z, acc.z);
    acc.w = fmaf(xv, w.w, acc.w);
  }
  float4 g4 = ((const float4*)gam)[sub];
  float4 be4 = ((const float4*)bet)[sub];
  float4 rm4 = ((const float4*)rm)[sub];
  float4 rv4 = ((const float4*)rv)[sub];
  float scx = g4.x * rsqrtf(rv4.x + EPS), shx = be4.x - rm4.x * scx;
  float scy = g4.y * rsqrtf(rv4.y + EPS), shy = be4.y - rm4.y * scy;
  float scz = g4.z * rsqrtf(rv4.z + EPS), shz = be4.z - rm4.z * scz;
  float scw = g4.w * rsqrtf(rv4.w + EPS), shw = be4.w - rm4.w * scw;
  float4 o;
  o.x = fmaxf(fmaf(acc.x, scx, shx), 0.f);
  o.y = fmaxf(fmaf(acc.y, scy, shy), 0.f);
  o.z = fmaxf(fmaf(acc.z, scz, shz), 0.f);
  o.w = fmaxf(fmaf(acc.w, scw, shw), 0.f);
  if (SCALE_OUT) { o.x *= d; o.y *= d; o.z *= d; o.w *= d; }
  out[(size_t)n * 16 + sub] = o;
}

// ---------- fused pooling + MLP: one block per graph, no atomics ----------
__device__ __forceinline__ int lower_bound(const int* __restrict__ b, int target) {
  int lo = 0, hi = NN;
  while (lo < hi) {
    int m = (lo + hi) >> 1;
    if (b[m] < target) lo = m + 1; else hi = m;
  }
  return lo;
}

__global__ void k_poolmlp(const float* __restrict__ feat, const int* __restrict__ bidx,
                          const float* __restrict__ mW1, const float* __restrict__ mb1,
                          const float* __restrict__ mW2, const float* __restrict__ mb2,
                          const float* __restrict__ mW3, const float* __restrict__ mb3,
                          float* __restrict__ out) {
  __shared__ float ssum[4][64], smax[4][64], xg[128], h1[32], h2[16];
  int g = blockIdx.x, t = threadIdx.x;  // 256 threads
  int c = t & 63, q = t >> 6;
  int lo = lower_bound(bidx, g);
  int hi = lower_bound(bidx, g + 1);
  float s = 0.f, m = 0.f;  // feat >= 0 post-ReLU; empty graph -> 0 matches reference
  for (int i = lo + q; i < hi; i += 4) {
    float v = feat[(size_t)i * 64 + c];
    s += v;
    m = fmaxf(m, v);
  }
  ssum[q][c] = s;
  smax[q][c] = m;
  __syncthreads();
  if (q == 0) {
    float cs = ssum[0][c] + ssum[1][c] + ssum[2][c] + ssum[3][c];
    float cm = fmaxf(fmaxf(smax[0][c], smax[1][c]), fmaxf(smax[2][c], smax[3][c]));
    float cnt = fmaxf((float)(hi - lo), 1.0f);
    xg[c] = cs / cnt;
    xg[64 + c] = cm;
  }
  __syncthreads();
  if (t < 32) {
    float a = mb1[t];
    for (int k = 0; k < 128; ++k) a = fmaf(xg[k], mW1[k * 32 + t], a);
    h1[t] = fmaxf(a, 0.f);
  }
  __syncthreads();
  if (t < 16) {
    float a = mb2[t];
    for (int k = 0; k < 32; ++k) a = fmaf(h1[k], mW2[k * 16 + t], a);
    h2[t] = fmaxf(a, 0.f);
  }
  __syncthreads();
  if (t == 0) {
    float a = mb3[0];
    for (int k = 0; k < 16; ++k) a = fmaf(h2[k], mW3[k], a);
    out[g] = a;
  }
}

extern "C" void kernel_launch(void* const* d_in, const int* in_sizes, int n_in,
                              void* d_out, int out_size, void* d_ws, size_t ws_size,
                              hipStream_t stream) {
  const float* x = (const float*)d_in[0];
  const int* ei = (const int*)d_in[1];
  const int* bidx = (const int*)d_in[2];
  const float *W[3], *b[3], *gam[3], *bet[3], *rm[3], *rv[3];
  for (int l = 0; l < 3; ++l) {
    W[l] = (const float*)d_in[3 + 6 * l];
    b[l] = (const float*)d_in[4 + 6 * l];
    gam[l] = (const float*)d_in[5 + 6 * l];
    bet[l] = (const float*)d_in[6 + 6 * l];
    rm[l] = (const float*)d_in[7 + 6 * l];
    rv[l] = (const float*)d_in[8 + 6 * l];
  }
  const float* mW1 = (const float*)d_in[21];
  const float* mb1 = (const float*)d_in[22];
  const float* mW2 = (const float*)d_in[23];
  const float* mb2 = (const float*)d_in[24];
  const float* mW3 = (const float*)d_in[25];
  const float* mb3 = (const float*)d_in[26];
  float* out = (float*)d_out;

  char* ws = (char*)d_ws;
  size_t off = 0;
  auto alloc = [&](size_t bytes) {
    void* p = ws + off;
    off = (off + bytes + 1023) & ~(size_t)1023;
    return p;
  };
  float* dinv = (float*)alloc(NN * 4);
  int* row = (int*)alloc((NN + 1) * 4);
  int* csr = (int*)alloc((size_t)EE * 4);
  int* bcnt = (int*)alloc(256 * 4);
  int* bbase = (int*)alloc(256 * 4);
  int* bfill = (int*)alloc(256 * 4);
  float4* xd = (float4*)alloc((size_t)NN * 16);
  float4* xt = (float4*)alloc((size_t)NN * 16);
  float* bufA = (float*)alloc((size_t)NN * 64 * 4);
  float* bufB = (float*)alloc((size_t)NN * 64 * 4);
  int2* tmp = (int2*)bufA;  // alias: tmp consumed by k_bucket before bufA is written

  hipMemsetAsync(bcnt, 0, 256 * 4, stream);

  // graph structure: bucket count -> scan -> bucketed dump -> per-bucket build
  k_bcnt<<<EBLK, 256, 0, stream>>>(ei, bcnt);
  k_bscan<<<1, 256, 0, stream>>>(bcnt, bbase, bfill, row);
  k_passA<<<EBLK, 256, 0, stream>>>(ei, bfill, tmp);
  k_bucket<<<KB2, 256, 0, stream>>>(tmp, bbase, x, csr, row, dinv, xd);

  int nb16 = (NN * 16 + 255) / 256;
  int nb64 = (NN * 64 + 255) / 256;

  // layer 0: node-parallel 3-ch aggregate, then fused matmul+BN+ReLU (pre-scaled out)
  k_agg3<<<NB256, 256, 0, stream>>>(xd, row, csr, dinv, xt);
  k_mm3bn<<<nb64, 256, 0, stream>>>(xt, W[0], b[0], gam[0], bet[0], rm[0], rv[0], dinv, bufA);
  // layer 1: fused gather + matmul + BN + ReLU, output pre-scaled for layer-2 gather
  k_layer2<true><<<nb16, 256, 0, stream>>>((const float4*)bufA, row, csr, dinv, W[1], b[1],
                                           gam[1], bet[1], rm[1], rv[1], (float4*)bufB);
  // layer 2: fused, unscaled output (final features)
  k_layer2<false><<<nb16, 256, 0, stream>>>((const float4*)bufB, row, csr, dinv, W[2], b[2],
                                            gam[2], bet[2], rm[2], rv[2], (float4*)bufA);
  // pooling (segmented, batch_idx sorted, no atomics) + graph MLP
  k_poolmlp<<<GG, 256, 0, stream>>>(bufA, bidx, mW1, mb1, mW2, mb2, mW3, mb3, out);
}

// Round 7
// 414.572 us; speedup vs baseline: 3.5231x; 1.0139x over previous
//
#include <hip/hip_runtime.h>

#define NN 100000
#define EE 1600000
#define GG 256
#define EPS 1e-5f
#define KB2 ((NN + 511) >> 9)        // 196 buckets of 512 dsts
#define EPB 4096                     // edges per block (bcnt/passA)
#define EBLK ((EE + EPB - 1) / EPB)  // 391
#define NB256 ((NN + 255) / 256)     // 391

// ---------- stage 1: per-bucket edge counts ----------
__global__ void k_bcnt(const int* __restrict__ ei, int* __restrict__ bcnt) {
  __shared__ int cnt[KB2];
  int t = threadIdx.x;
  for (int i = t; i < KB2; i += 256) cnt[i] = 0;
  __syncthreads();
  int e0 = blockIdx.x * EPB;
#pragma unroll
  for (int j = 0; j < 16; ++j) {
    int e = e0 + j * 256 + t;
    if (e < EE) atomicAdd(&cnt[ei[EE + e] >> 9], 1);
  }
  __syncthreads();
  for (int i = t; i < KB2; i += 256)
    if (cnt[i] > 0) atomicAdd(&bcnt[i], cnt[i]);
}

// ---------- stage 2: scan bucket counts -> bucket bases ----------
__global__ void k_bscan(const int* __restrict__ bcnt, int* __restrict__ bbase,
                        int* __restrict__ bfill, int* __restrict__ row) {
  __shared__ int s[256];
  int t = threadIdx.x;
  int v = (t < KB2) ? bcnt[t] : 0;
  s[t] = v;
  __syncthreads();
  for (int off = 1; off < 256; off <<= 1) {
    int add = (t >= off) ? s[t - off] : 0;
    __syncthreads();
    s[t] += add;
    __syncthreads();
  }
  if (t < KB2) {
    int e = s[t] - v;
    bbase[t] = e;
    bfill[t] = e;
  }
  if (t == 0) {
    bbase[KB2] = EE;
    row[NN] = EE;
  }
}

// ---------- stage 3: bucketed dump of (src,dst) pairs ----------
__global__ void k_passA(const int* __restrict__ ei, int* __restrict__ bfill,
                        int2* __restrict__ tmp) {
  __shared__ int cnt[KB2], cur[KB2], base[KB2];
  int t = threadIdx.x;
  for (int b = t; b < KB2; b += 256) { cnt[b] = 0; cur[b] = 0; }
  __syncthreads();
  int e0 = blockIdx.x * EPB;
  int myb[16];
#pragma unroll
  for (int j = 0; j < 16; ++j) {
    int e = e0 + j * 256 + t;
    int bb = -1;
    if (e < EE) bb = ei[EE + e] >> 9;
    myb[j] = bb;
    if (bb >= 0) atomicAdd(&cnt[bb], 1);
  }
  __syncthreads();
  for (int b = t; b < KB2; b += 256)
    if (cnt[b] > 0) base[b] = atomicAdd(&bfill[b], cnt[b]);
  __syncthreads();
#pragma unroll
  for (int j = 0; j < 16; ++j) {
    int e = e0 + j * 256 + t;
    int bb = myb[j];
    if (bb >= 0) {
      int slot = base[bb] + atomicAdd(&cur[bb], 1);
      tmp[slot] = make_int2(ei[e], ei[EE + e]);
    }
  }
}

// ---------- stage 4: per-bucket hist+scan+scatter; emits row, dinv, xd, csr ----------
__global__ void k_bucket(const int2* __restrict__ tmp, const int* __restrict__ bbase,
                         const float* __restrict__ x, int* __restrict__ csr,
                         int* __restrict__ row, float* __restrict__ dinv,
                         float4* __restrict__ xd) {
  __shared__ int cnt[512], s[512], fillp[512];
  int b = blockIdx.x, t = threadIdx.x;
  int nb = b << 9;
  int e0 = bbase[b], e1 = bbase[b + 1];
  cnt[t] = 0;
  cnt[t + 256] = 0;
  __syncthreads();
  for (int e = e0 + t; e < e1; e += 256) atomicAdd(&cnt[tmp[e].y & 511], 1);
  __syncthreads();
  s[t] = cnt[t];
  s[t + 256] = cnt[t + 256];
  __syncthreads();
  for (int off = 1; off < 512; off <<= 1) {
    int i1 = t + 256;
    int v0 = (t >= off) ? s[t - off] : 0;
    int v1 = (i1 >= off) ? s[i1 - off] : 0;
    __syncthreads();
    s[t] += v0;
    s[i1] += v1;
    __syncthreads();
  }
#pragma unroll
  for (int k = 0; k < 2; ++k) {
    int i = t + k * 256;
    int excl = s[i] - cnt[i];
    fillp[i] = excl;
    int dst = nb + i;
    if (dst < NN) {
      row[dst] = e0 + excl;
      float d = rsqrtf((float)cnt[i] + 1.0f);
      dinv[dst] = d;
      xd[dst] = make_float4(x[dst * 3] * d, x[dst * 3 + 1] * d, x[dst * 3 + 2] * d, 0.f);
    }
  }
  __syncthreads();
  for (int e = e0 + t; e < e1; e += 256) {
    int2 ed = tmp[e];
    int slot = atomicAdd(&fillp[ed.y & 511], 1);
    csr[e0 + slot] = ed.x;  // plain src index
  }
}

// ---------- layer 0: fused 3-ch aggregate + 3->64 matmul + BN + ReLU + pre-scale ----------
__global__ void k_agg3f(const float4* __restrict__ xd, const int* __restrict__ row,
                        const int* __restrict__ csr, const float* __restrict__ dinv,
                        const float* __restrict__ W, const float* __restrict__ b,
                        const float* __restrict__ gam, const float* __restrict__ bet,
                        const float* __restrict__ rm, const float* __restrict__ rv,
                        float4* __restrict__ out) {
  int n = blockIdx.x * 256 + threadIdx.x;
  if (n >= NN) return;
  int s0 = row[n], s1 = row[n + 1];
  float4 a = xd[n];
  float ax = a.x, ay = a.y, az = a.z;
  int i = s0;
  for (; i + 16 <= s1; i += 16) {
    int idx[16];
#pragma unroll
    for (int j = 0; j < 16; ++j) idx[j] = csr[i + j];
    float4 v[16];
#pragma unroll
    for (int j = 0; j < 16; ++j) v[j] = xd[idx[j]];
#pragma unroll
    for (int j = 0; j < 16; ++j) { ax += v[j].x; ay += v[j].y; az += v[j].z; }
  }
  for (; i + 8 <= s1; i += 8) {
    int idx[8];
#pragma unroll
    for (int j = 0; j < 8; ++j) idx[j] = csr[i + j];
    float4 v[8];
#pragma unroll
    for (int j = 0; j < 8; ++j) v[j] = xd[idx[j]];
#pragma unroll
    for (int j = 0; j < 8; ++j) { ax += v[j].x; ay += v[j].y; az += v[j].z; }
  }
  for (; i < s1; ++i) {
    float4 v = xd[csr[i]];
    ax += v.x; ay += v.y; az += v.z;
  }
  float d = dinv[n];
  float t0 = ax * d, t1 = ay * d, t2 = az * d;
  const float4* W4 = (const float4*)W;
  const float4* b4 = (const float4*)b;
  const float4* g4p = (const float4*)gam;
  const float4* be4p = (const float4*)bet;
  const float4* rm4p = (const float4*)rm;
  const float4* rv4p = (const float4*)rv;
#pragma unroll
  for (int c4 = 0; c4 < 16; ++c4) {
    float4 w0 = W4[c4], w1 = W4[16 + c4], w2 = W4[32 + c4];
    float4 bb = b4[c4], g4 = g4p[c4], be4 = be4p[c4], rm4 = rm4p[c4], rv4 = rv4p[c4];
    float4 o;
    o.x = fmaf(t0, w0.x, fmaf(t1, w1.x, fmaf(t2, w2.x, bb.x)));
    o.y = fmaf(t0, w0.y, fmaf(t1, w1.y, fmaf(t2, w2.y, bb.y)));
    o.z = fmaf(t0, w0.z, fmaf(t1, w1.z, fmaf(t2, w2.z, bb.z)));
    o.w = fmaf(t0, w0.w, fmaf(t1, w1.w, fmaf(t2, w2.w, bb.w)));
    float scx = g4.x * rsqrtf(rv4.x + EPS), shx = be4.x - rm4.x * scx;
    float scy = g4.y * rsqrtf(rv4.y + EPS), shy = be4.y - rm4.y * scy;
    float scz = g4.z * rsqrtf(rv4.z + EPS), shz = be4.z - rm4.z * scz;
    float scw = g4.w * rsqrtf(rv4.w + EPS), shw = be4.w - rm4.w * scw;
    o.x = fmaxf(fmaf(o.x, scx, shx), 0.f) * d;
    o.y = fmaxf(fmaf(o.y, scy, shy), 0.f) * d;
    o.z = fmaxf(fmaf(o.z, scz, shz), 0.f) * d;
    o.w = fmaxf(fmaf(o.w, scw, shw), 0.f) * d;
    out[(size_t)n * 16 + c4] = o;
  }
}

// ---------- fused layer: deep-pipelined gather + LDS exchange + matmul + BN + ReLU ----------
template <bool SCALE_OUT>
__global__ void k_layer2(const float4* __restrict__ xs, const int* __restrict__ row,
                         const int* __restrict__ csr, const float* __restrict__ dinv,
                         const float* __restrict__ W, const float* __restrict__ b,
                         const float* __restrict__ gam, const float* __restrict__ bet,
                         const float* __restrict__ rm, const float* __restrict__ rv,
                         float4* __restrict__ out) {
  __shared__ float sh[16][68];
  int t = blockIdx.x * 256 + threadIdx.x;
  int n = t >> 4, sub = t & 15;
  int local = threadIdx.x >> 4;
  if (n >= NN) return;  // N = 16*6250 exactly: no partial blocks, barrier-safe
  int s0 = row[n], s1 = row[n + 1];
  float4 a = xs[(size_t)n * 16 + sub];
  int i = s0;
  // 16-deep batch: one latency round-trip covers the average degree
  for (; i + 16 <= s1; i += 16) {
    int idx[16];
#pragma unroll
    for (int j = 0; j < 16; ++j) idx[j] = csr[i + j];
    float4 v[16];
#pragma unroll
    for (int j = 0; j < 16; ++j) v[j] = xs[(size_t)idx[j] * 16 + sub];
#pragma unroll
    for (int j = 0; j < 16; ++j) {
      a.x += v[j].x; a.y += v[j].y; a.z += v[j].z; a.w += v[j].w;
    }
  }
  for (; i + 8 <= s1; i += 8) {
    int idx[8];
#pragma unroll
    for (int j = 0; j < 8; ++j) idx[j] = csr[i + j];
    float4 v[8];
#pragma unroll
    for (int j = 0; j < 8; ++j) v[j] = xs[(size_t)idx[j] * 16 + sub];
#pragma unroll
    for (int j = 0; j < 8; ++j) {
      a.x += v[j].x; a.y += v[j].y; a.z += v[j].z; a.w += v[j].w;
    }
  }
  for (; i + 4 <= s1; i += 4) {
    int idx[4];
#pragma unroll
    for (int j = 0; j < 4; ++j) idx[j] = csr[i + j];
    float4 v[4];
#pragma unroll
    for (int j = 0; j < 4; ++j) v[j] = xs[(size_t)idx[j] * 16 + sub];
#pragma unroll
    for (int j = 0; j < 4; ++j) {
      a.x += v[j].x; a.y += v[j].y; a.z += v[j].z; a.w += v[j].w;
    }
  }
  for (; i < s1; ++i) {
    float4 v = xs[(size_t)csr[i] * 16 + sub];
    a.x += v.x; a.y += v.y; a.z += v.z; a.w += v.w;
  }
  float d = dinv[n];
  sh[local][sub * 4 + 0] = a.x * d;
  sh[local][sub * 4 + 1] = a.y * d;
  sh[local][sub * 4 + 2] = a.z * d;
  sh[local][sub * 4 + 3] = a.w * d;
  __syncthreads();
  const float4* W4 = (const float4*)W;
  float4 acc = ((const float4*)b)[sub];
#pragma unroll 8
  for (int k = 0; k < 64; ++k) {
    float xv = sh[local][k];
    float4 w = W4[k * 16 + sub];
    acc.x = fmaf(xv, w.x, acc.x);
    acc.y = fmaf(xv, w.y, acc.y);
    acc.z = fmaf(xv, w.z, acc.z);
    acc.w = fmaf(xv, w.w, acc.w);
  }
  float4 g4 = ((const float4*)gam)[sub];
  float4 be4 = ((const float4*)bet)[sub];
  float4 rm4 = ((const float4*)rm)[sub];
  float4 rv4 = ((const float4*)rv)[sub];
  float scx = g4.x * rsqrtf(rv4.x + EPS), shx = be4.x - rm4.x * scx;
  float scy = g4.y * rsqrtf(rv4.y + EPS), shy = be4.y - rm4.y * scy;
  float scz = g4.z * rsqrtf(rv4.z + EPS), shz = be4.z - rm4.z * scz;
  float scw = g4.w * rsqrtf(rv4.w + EPS), shw = be4.w - rm4.w * scw;
  float4 o;
  o.x = fmaxf(fmaf(acc.x, scx, shx), 0.f);
  o.y = fmaxf(fmaf(acc.y, scy, shy), 0.f);
  o.z = fmaxf(fmaf(acc.z, scz, shz), 0.f);
  o.w = fmaxf(fmaf(acc.w, scw, shw), 0.f);
  if (SCALE_OUT) { o.x *= d; o.y *= d; o.z *= d; o.w *= d; }
  out[(size_t)n * 16 + sub] = o;
}

// ---------- fused pooling + MLP: one block per graph, no atomics ----------
__device__ __forceinline__ int lower_bound(const int* __restrict__ b, int target) {
  int lo = 0, hi = NN;
  while (lo < hi) {
    int m = (lo + hi) >> 1;
    if (b[m] < target) lo = m + 1; else hi = m;
  }
  return lo;
}

__global__ void k_poolmlp(const float* __restrict__ feat, const int* __restrict__ bidx,
                          const float* __restrict__ mW1, const float* __restrict__ mb1,
                          const float* __restrict__ mW2, const float* __restrict__ mb2,
                          const float* __restrict__ mW3, const float* __restrict__ mb3,
                          float* __restrict__ out) {
  __shared__ float ssum[4][64], smax[4][64], xg[128], h1[32], h2[16];
  int g = blockIdx.x, t = threadIdx.x;  // 256 threads
  int c = t & 63, q = t >> 6;
  int lo = lower_bound(bidx, g);
  int hi = lower_bound(bidx, g + 1);
  float s = 0.f, m = 0.f;  // feat >= 0 post-ReLU; empty graph -> 0 matches reference
  for (int i = lo + q; i < hi; i += 4) {
    float v = feat[(size_t)i * 64 + c];
    s += v;
    m = fmaxf(m, v);
  }
  ssum[q][c] = s;
  smax[q][c] = m;
  __syncthreads();
  if (q == 0) {
    float cs = ssum[0][c] + ssum[1][c] + ssum[2][c] + ssum[3][c];
    float cm = fmaxf(fmaxf(smax[0][c], smax[1][c]), fmaxf(smax[2][c], smax[3][c]));
    float cnt = fmaxf((float)(hi - lo), 1.0f);
    xg[c] = cs / cnt;
    xg[64 + c] = cm;
  }
  __syncthreads();
  if (t < 32) {
    float a = mb1[t];
    for (int k = 0; k < 128; ++k) a = fmaf(xg[k], mW1[k * 32 + t], a);
    h1[t] = fmaxf(a, 0.f);
  }
  __syncthreads();
  if (t < 16) {
    float a = mb2[t];
    for (int k = 0; k < 32; ++k) a = fmaf(h1[k], mW2[k * 16 + t], a);
    h2[t] = fmaxf(a, 0.f);
  }
  __syncthreads();
  if (t == 0) {
    float a = mb3[0];
    for (int k = 0; k < 16; ++k) a = fmaf(h2[k], mW3[k], a);
    out[g] = a;
  }
}

extern "C" void kernel_launch(void* const* d_in, const int* in_sizes, int n_in,
                              void* d_out, int out_size, void* d_ws, size_t ws_size,
                              hipStream_t stream) {
  const float* x = (const float*)d_in[0];
  const int* ei = (const int*)d_in[1];
  const int* bidx = (const int*)d_in[2];
  const float *W[3], *b[3], *gam[3], *bet[3], *rm[3], *rv[3];
  for (int l = 0; l < 3; ++l) {
    W[l] = (const float*)d_in[3 + 6 * l];
    b[l] = (const float*)d_in[4 + 6 * l];
    gam[l] = (const float*)d_in[5 + 6 * l];
    bet[l] = (const float*)d_in[6 + 6 * l];
    rm[l] = (const float*)d_in[7 + 6 * l];
    rv[l] = (const float*)d_in[8 + 6 * l];
  }
  const float* mW1 = (const float*)d_in[21];
  const float* mb1 = (const float*)d_in[22];
  const float* mW2 = (const float*)d_in[23];
  const float* mb2 = (const float*)d_in[24];
  const float* mW3 = (const float*)d_in[25];
  const float* mb3 = (const float*)d_in[26];
  float* out = (float*)d_out;

  char* ws = (char*)d_ws;
  size_t off = 0;
  auto alloc = [&](size_t bytes) {
    void* p = ws + off;
    off = (off + bytes + 1023) & ~(size_t)1023;
    return p;
  };
  float* dinv = (float*)alloc(NN * 4);
  int* row = (int*)alloc((NN + 1) * 4);
  int* csr = (int*)alloc((size_t)EE * 4);
  int* bcnt = (int*)alloc(256 * 4);
  int* bbase = (int*)alloc(256 * 4);
  int* bfill = (int*)alloc(256 * 4);
  float4* xd = (float4*)alloc((size_t)NN * 16);
  float* bufA = (float*)alloc((size_t)NN * 64 * 4);
  float* bufB = (float*)alloc((size_t)NN * 64 * 4);
  int2* tmp = (int2*)bufA;  // alias: tmp consumed by k_bucket before bufA is written

  hipMemsetAsync(bcnt, 0, 256 * 4, stream);

  // graph structure: bucket count -> scan -> bucketed dump -> per-bucket build
  k_bcnt<<<EBLK, 256, 0, stream>>>(ei, bcnt);
  k_bscan<<<1, 256, 0, stream>>>(bcnt, bbase, bfill, row);
  k_passA<<<EBLK, 256, 0, stream>>>(ei, bfill, tmp);
  k_bucket<<<KB2, 256, 0, stream>>>(tmp, bbase, x, csr, row, dinv, xd);

  int nb16 = (NN * 16 + 255) / 256;

  // layer 0: fused aggregate + 3->64 matmul + BN + ReLU (pre-scaled out)
  k_agg3f<<<NB256, 256, 0, stream>>>(xd, row, csr, dinv, W[0], b[0], gam[0], bet[0],
                                     rm[0], rv[0], (float4*)bufA);
  // layer 1: fused gather + matmul + BN + ReLU, output pre-scaled for layer-2 gather
  k_layer2<true><<<nb16, 256, 0, stream>>>((const float4*)bufA, row, csr, dinv, W[1], b[1],
                                           gam[1], bet[1], rm[1], rv[1], (float4*)bufB);
  // layer 2: fused, unscaled output (final features)
  k_layer2<false><<<nb16, 256, 0, stream>>>((const float4*)bufB, row, csr, dinv, W[2], b[2],
                                            gam[2], bet[2], rm[2], rv[2], (float4*)bufA);
  // pooling (segmented, batch_idx sorted, no atomics) + graph MLP
  k_poolmlp<<<GG, 256, 0, stream>>>(bufA, bidx, mW1, mb1, mW2, mb2, mW3, mb3, out);
}